// Round 3
// baseline (591.949 us; speedup 1.0000x reference)
//
#include <hip/hip_runtime.h>
#include <math.h>

#define H2 128

typedef unsigned short ushort_t;
typedef unsigned int uint_t;

static __device__ inline uint_t pack_bf16x2(float a, float b) {
  uint_t ua = __float_as_uint(a); ua += 0x7fffu + ((ua >> 16) & 1u);
  uint_t ub = __float_as_uint(b); ub += 0x7fffu + ((ub >> 16) & 1u);
  return (ua >> 16) | (ub & 0xffff0000u);
}
static __device__ inline float bf_lo(uint_t u) { return __uint_as_float(u << 16); }
static __device__ inline float bf_hi(uint_t u) { return __uint_as_float(u & 0xffff0000u); }

// ---------------- init ----------------
__global__ __launch_bounds__(256) void k_init(int* __restrict__ deg, int* __restrict__ cursor,
                                              float* __restrict__ pool, int* __restrict__ total, int N) {
  int i = blockIdx.x * 256 + threadIdx.x;
  if (i < N) { deg[i] = 1; cursor[i] = 0; }
  if (i < H2) pool[i] = 0.f;
  if (i == 0) *total = 0;
}

// ---------------- in-degree histogram ----------------
__global__ __launch_bounds__(256) void k_degree(const int* __restrict__ col, int* __restrict__ deg, int E) {
  int e = blockIdx.x * 256 + threadIdx.x;
  if (e < E) atomicAdd(&deg[col[e]], 1);
}

// ---------------- dis = rsqrt(deg); col_off via wave-prefix + 1 atomic/wave ----------------
__global__ __launch_bounds__(256) void k_offs(const int* __restrict__ deg, float* __restrict__ dis,
                                              int* __restrict__ col_off, int* __restrict__ total, int N) {
  int i = blockIdx.x * 256 + threadIdx.x;
  int lane = threadIdx.x & 63;
  int d = (i < N) ? deg[i] : 1;
  if (i < N) dis[i] = rsqrtf((float)d);
  int v = d - 1;
  int pref = v;
#pragma unroll
  for (int s = 1; s < 64; s <<= 1) {
    int t = __shfl_up(pref, s, 64);
    if (lane >= s) pref += t;
  }
  int wavesum = __shfl(pref, 63, 64);
  int base = 0;
  if (lane == 63) base = atomicAdd(total, wavesum);
  base = __shfl(base, 63, 64);
  if (i < N) col_off[i] = base + pref - v;
}

// ---------------- scatter edges into CSR-by-destination ----------------
__global__ __launch_bounds__(256) void k_scatter(const int* __restrict__ row, const int* __restrict__ col,
                                                 const int* __restrict__ col_off, int* __restrict__ cursor,
                                                 int* __restrict__ csr_src, int E) {
  int e = blockIdx.x * 256 + threadIdx.x;
  if (e < E) {
    int c = col[e];
    int p = col_off[c] + atomicAdd(&cursor[c], 1);
    csr_src[p] = row[e];
  }
}

// ---------------- layer-1 aggregation of raw x ----------------
__global__ __launch_bounds__(256) void k_l1gather(const float* __restrict__ x, const int* __restrict__ csr_src,
                                                  const int* __restrict__ col_off, const int* __restrict__ deg,
                                                  const float* __restrict__ dis, float* __restrict__ aggx, int N) {
  int c = blockIdx.x * 256 + threadIdx.x;
  if (c >= N) return;
  float dc = dis[c];
  int base = col_off[c];
  int cnt = deg[c] - 1;
  float4 xs = ((const float4*)x)[c];
  float ax = 0.f, ay = 0.f, az = 0.f, aw = 0.f;
  for (int j = 0; j < cnt; ++j) {
    int r = csr_src[base + j];
    float w = dis[r];
    float4 xr = ((const float4*)x)[r];
    ax = fmaf(w, xr.x, ax);
    ay = fmaf(w, xr.y, ay);
    az = fmaf(w, xr.z, az);
    aw = fmaf(w, xr.w, aw);
  }
  float d2 = dc * dc;
  float4 o;
  o.x = fmaf(dc, ax, d2 * xs.x);
  o.y = fmaf(dc, ay, d2 * xs.y);
  o.z = fmaf(dc, az, d2 * xs.z);
  o.w = fmaf(dc, aw, d2 * xs.w);
  ((float4*)aggx)[c] = o;
}

// ---------------- fused: h1 = relu(aggx@W1+b1) in LDS, t2 = h1@W2 (bf16, 8 column-slabs) ----------------
// t2 slab layout: slab s holds dims [16s,16s+16) for all nodes: t2[((s*N + node)*16 + within)]
__global__ __launch_bounds__(256) void k_gemm(const float* __restrict__ aggx, const float* __restrict__ W1,
                                              const float* __restrict__ b1, const float* __restrict__ W2,
                                              ushort_t* __restrict__ t2, int N) {
  __shared__ float ax[64][4];
  __shared__ float h1s[64][33];
  __shared__ __align__(16) float w2s[32][128];
  int tid = threadIdx.x;
  int node0 = blockIdx.x * 64;
  {
    int n = tid >> 2, k = tid & 3;
    int node = node0 + n;
    ax[n][k] = (node < N) ? aggx[node * 4 + k] : 0.f;
  }
  __syncthreads();
  float acc[8][4];
#pragma unroll
  for (int r = 0; r < 8; ++r)
#pragma unroll
    for (int cc = 0; cc < 4; ++cc) acc[r][cc] = 0.f;
  int tx = tid & 31, ty = tid >> 5;
  for (int it = 0; it < 8; ++it) {
#pragma unroll
    for (int q = 0; q < 8; ++q) {
      int lin = tid + 256 * q;
      int n = lin >> 5, kk = lin & 31;
      int j = it * 32 + kk;
      float v = b1[j];
      v = fmaf(ax[n][0], W1[j], v);
      v = fmaf(ax[n][1], W1[256 + j], v);
      v = fmaf(ax[n][2], W1[512 + j], v);
      v = fmaf(ax[n][3], W1[768 + j], v);
      h1s[n][kk] = fmaxf(v, 0.f);
    }
#pragma unroll
    for (int q = 0; q < 16; ++q) {
      int lin = tid + 256 * q;
      int kk = lin >> 7, cc = lin & 127;
      w2s[kk][cc] = W2[(it * 32 + kk) * 128 + cc];
    }
    __syncthreads();
#pragma unroll
    for (int kk = 0; kk < 32; ++kk) {
      float4 bv = *(const float4*)&w2s[kk][tx * 4];
#pragma unroll
      for (int r = 0; r < 8; ++r) {
        float a = h1s[ty * 8 + r][kk];
        acc[r][0] = fmaf(a, bv.x, acc[r][0]);
        acc[r][1] = fmaf(a, bv.y, acc[r][1]);
        acc[r][2] = fmaf(a, bv.z, acc[r][2]);
        acc[r][3] = fmaf(a, bv.w, acc[r][3]);
      }
    }
    __syncthreads();
  }
  int slice = tx >> 2;
#pragma unroll
  for (int r = 0; r < 8; ++r) {
    int node = node0 + ty * 8 + r;
    if (node < N) {
      uint_t p0 = pack_bf16x2(acc[r][0], acc[r][1]);
      uint_t p1 = pack_bf16x2(acc[r][2], acc[r][3]);
      uint2 o = make_uint2(p0, p1);
      size_t off = ((size_t)slice * N + node) * 16 + (tx & 3) * 4;
      *(uint2*)(t2 + off) = o;
    }
  }
}

// ---------------- layer-2 aggregation over L2-resident column slab + relu + mean-pool ----------------
// slice = blockIdx%8 pins each 3.2MB slab to one XCD's L2 (round-robin dispatch heuristic).
// Wave = 8 edge-groups x 8 lanes; lane covers dims 2p,2p+1 of its slice; edge idx+dis
// preloaded 64-wide and distributed by shfl so the only in-loop memory op is the t2 dword.
__global__ __launch_bounds__(256) void k_agg2(const int* __restrict__ csr_src, const int* __restrict__ col_off,
                                              const int* __restrict__ deg, const float* __restrict__ dis,
                                              const ushort_t* __restrict__ t2, const float* __restrict__ b2,
                                              float* __restrict__ pool, int N) {
  const int slice = blockIdx.x & 7;
  const int wave = threadIdx.x >> 6;
  const int lane = threadIdx.x & 63;
  const int g = lane >> 3;   // edge group
  const int p = lane & 7;    // dim pair within slice
  const ushort_t* slab = t2 + (size_t)slice * N * 16;
  int gw = (blockIdx.x >> 3) * 4 + wave;
  int nw = (gridDim.x >> 3) * 4;
  float b0 = b2[slice * 16 + 2 * p];
  float b1v = b2[slice * 16 + 2 * p + 1];
  float p0 = 0.f, p1 = 0.f;
  for (int c = gw; c < N; c += nw) {
    float dc = dis[c];
    int base = col_off[c];
    int cnt = deg[c] - 1;
    float a0 = 0.f, a1 = 0.f;
    for (int j0 = 0; j0 < cnt; j0 += 64) {
      int nb = min(64, cnt - j0);
      int r_l = (lane < nb) ? csr_src[base + j0 + lane] : c;
      float d_l = (lane < nb) ? dis[r_l] : 0.f;
#pragma unroll 4
      for (int jj = 0; jj < nb; jj += 8) {
        int e = jj + g;
        int r = __shfl(r_l, e, 64);
        float w = __shfl(d_l, e, 64);   // 0 for tail lanes -> no contribution
        uint_t u = *(const uint_t*)(slab + (size_t)r * 16 + 2 * p);
        a0 = fmaf(w, bf_lo(u), a0);
        a1 = fmaf(w, bf_hi(u), a1);
      }
    }
    // butterfly reduce over the 8 edge-groups
    a0 += __shfl_xor(a0, 8, 64);  a1 += __shfl_xor(a1, 8, 64);
    a0 += __shfl_xor(a0, 16, 64); a1 += __shfl_xor(a1, 16, 64);
    a0 += __shfl_xor(a0, 32, 64); a1 += __shfl_xor(a1, 32, 64);
    uint_t us = *(const uint_t*)(slab + (size_t)c * 16 + 2 * p);
    float d2 = dc * dc;
    p0 += fmaxf(fmaf(dc, a0, fmaf(d2, bf_lo(us), b0)), 0.f);
    p1 += fmaxf(fmaf(dc, a1, fmaf(d2, bf_hi(us), b1v)), 0.f);
  }
  __shared__ float red[4][8][2];
  if (g == 0) { red[wave][p][0] = p0; red[wave][p][1] = p1; }
  __syncthreads();
  if (threadIdx.x < 16) {
    int pp = threadIdx.x >> 1, io = threadIdx.x & 1;
    float s = red[0][pp][io] + red[1][pp][io] + red[2][pp][io] + red[3][pp][io];
    atomicAdd(&pool[slice * 16 + 2 * pp + io], s);
  }
}

// ---------------- final ----------------
__global__ __launch_bounds__(128) void k_final(const float* __restrict__ pool, const float* __restrict__ Wl,
                                               const float* __restrict__ bl, float* __restrict__ out, float invN) {
  __shared__ float red[128];
  int t = threadIdx.x;
  red[t] = pool[t] * invN * Wl[t];
  __syncthreads();
  for (int s = 64; s > 0; s >>= 1) {
    if (t < s) red[t] += red[t + s];
    __syncthreads();
  }
  if (t == 0) out[0] = 1.f / (1.f + expf(-(red[0] + bl[0])));
}

extern "C" void kernel_launch(void* const* d_in, const int* in_sizes, int n_in,
                              void* d_out, int out_size, void* d_ws, size_t ws_size,
                              hipStream_t stream) {
  const float* x  = (const float*)d_in[0];
  const int*   ei = (const int*)d_in[1];
  const float* W1 = (const float*)d_in[2];
  const float* b1 = (const float*)d_in[3];
  const float* W2 = (const float*)d_in[4];
  const float* b2 = (const float*)d_in[5];
  const float* Wl = (const float*)d_in[6];
  const float* bl = (const float*)d_in[7];
  int N = in_sizes[0] / 4;
  int E = in_sizes[1] / 2;
  const int* row = ei;
  const int* col = ei + E;

  char* w = (char*)d_ws;
  size_t off = 0;
  auto alloc = [&](size_t bytes) {
    void* p = w + off;
    off += (bytes + 255) & ~(size_t)255;
    return p;
  };
  int*      deg     = (int*)alloc((size_t)N * 4);
  float*    dis     = (float*)alloc((size_t)N * 4);
  int*      col_off = (int*)alloc((size_t)N * 4);
  int*      cursor  = (int*)alloc((size_t)N * 4);
  int*      csr_src = (int*)alloc((size_t)E * 4);
  float*    aggx    = (float*)alloc((size_t)N * 16);
  ushort_t* t2      = (ushort_t*)alloc((size_t)N * H2 * 2);
  float*    pool    = (float*)alloc(H2 * 4);
  int*      total   = (int*)alloc(4);
  (void)ws_size; (void)n_in; (void)out_size;

  int gN = (N + 255) / 256;
  int gE = (E + 255) / 256;

  k_init<<<gN, 256, 0, stream>>>(deg, cursor, pool, total, N);
  k_degree<<<gE, 256, 0, stream>>>(col, deg, E);
  k_offs<<<gN, 256, 0, stream>>>(deg, dis, col_off, total, N);
  k_scatter<<<gE, 256, 0, stream>>>(row, col, col_off, cursor, csr_src, E);
  k_l1gather<<<gN, 256, 0, stream>>>(x, csr_src, col_off, deg, dis, aggx, N);
  k_gemm<<<(N + 63) / 64, 256, 0, stream>>>(aggx, W1, b1, W2, t2, N);
  k_agg2<<<2048, 256, 0, stream>>>(csr_src, col_off, deg, dis, t2, b2, pool, N);
  k_final<<<1, 128, 0, stream>>>(pool, Wl, bl, (float*)d_out, 1.0f / (float)N);
}

// Round 4
// 475.402 us; speedup vs baseline: 1.2452x; 1.2452x over previous
//
#include <hip/hip_runtime.h>
#include <math.h>

#define H2 128

typedef unsigned short ushort_t;
typedef unsigned int uint_t;
typedef __attribute__((ext_vector_type(8))) short bf16x8;
typedef __attribute__((ext_vector_type(4))) float f32x4;

static __device__ inline ushort_t bf16_1(float f) {
  uint_t u = __float_as_uint(f);
  u += 0x7fffu + ((u >> 16) & 1u);
  return (ushort_t)(u >> 16);
}
static __device__ inline float bf_lo(uint_t u) { return __uint_as_float(u << 16); }
static __device__ inline float bf_hi(uint_t u) { return __uint_as_float(u & 0xffff0000u); }

// ---------------- init ----------------
__global__ __launch_bounds__(256) void k_init(int* __restrict__ deg, int* __restrict__ cursor,
                                              float* __restrict__ pool, int* __restrict__ total, int N) {
  int i = blockIdx.x * 256 + threadIdx.x;
  if (i < N) { deg[i] = 1; cursor[i] = 0; }
  if (i < H2) pool[i] = 0.f;
  if (i == 0) *total = 0;
}

// ---------------- in-degree histogram ----------------
__global__ __launch_bounds__(256) void k_degree(const int* __restrict__ col, int* __restrict__ deg, int E) {
  int e = blockIdx.x * 256 + threadIdx.x;
  if (e < E) atomicAdd(&deg[col[e]], 1);
}

// ---------------- dis = rsqrt(deg); xs = dis*x; col_off via wave-prefix + 1 atomic/wave ----------------
__global__ __launch_bounds__(256) void k_offs(const int* __restrict__ deg, const float* __restrict__ x,
                                              float* __restrict__ dis, float* __restrict__ xs,
                                              int* __restrict__ col_off, int* __restrict__ total, int N) {
  int i = blockIdx.x * 256 + threadIdx.x;
  int lane = threadIdx.x & 63;
  int d = (i < N) ? deg[i] : 1;
  float di = rsqrtf((float)d);
  if (i < N) {
    dis[i] = di;
    float4 xv = ((const float4*)x)[i];
    float4 o = make_float4(di * xv.x, di * xv.y, di * xv.z, di * xv.w);
    ((float4*)xs)[i] = o;
  }
  int v = d - 1;
  int pref = v;
#pragma unroll
  for (int s = 1; s < 64; s <<= 1) {
    int t = __shfl_up(pref, s, 64);
    if (lane >= s) pref += t;
  }
  int wavesum = __shfl(pref, 63, 64);
  int base = 0;
  if (lane == 63) base = atomicAdd(total, wavesum);
  base = __shfl(base, 63, 64);
  if (i < N) col_off[i] = base + pref - v;
}

// ---------------- scatter edges into CSR-by-destination ----------------
__global__ __launch_bounds__(256) void k_scatter(const int* __restrict__ row, const int* __restrict__ col,
                                                 const int* __restrict__ col_off, int* __restrict__ cursor,
                                                 int* __restrict__ csr_src, int E) {
  int e = blockIdx.x * 256 + threadIdx.x;
  if (e < E) {
    int c = col[e];
    int p = col_off[c] + atomicAdd(&cursor[c], 1);
    csr_src[p] = row[e];
  }
}

// ---------------- layer-1 aggregation: aggx[c] = dc*(xs[c] + sum xs[r]) ----------------
__global__ __launch_bounds__(256) void k_l1gather(const float* __restrict__ xs, const int* __restrict__ csr_src,
                                                  const int* __restrict__ col_off, const int* __restrict__ deg,
                                                  const float* __restrict__ dis, float* __restrict__ aggx, int N) {
  int c = blockIdx.x * 256 + threadIdx.x;
  if (c >= N) return;
  float dc = dis[c];
  int base = col_off[c];
  int cnt = deg[c] - 1;
  float4 a = ((const float4*)xs)[c];
  int j = 0;
  for (; j + 4 <= cnt; j += 4) {
    int r0 = csr_src[base + j], r1 = csr_src[base + j + 1];
    int r2 = csr_src[base + j + 2], r3 = csr_src[base + j + 3];
    float4 v0 = ((const float4*)xs)[r0];
    float4 v1 = ((const float4*)xs)[r1];
    float4 v2 = ((const float4*)xs)[r2];
    float4 v3 = ((const float4*)xs)[r3];
    a.x += (v0.x + v1.x) + (v2.x + v3.x);
    a.y += (v0.y + v1.y) + (v2.y + v3.y);
    a.z += (v0.z + v1.z) + (v2.z + v3.z);
    a.w += (v0.w + v1.w) + (v2.w + v3.w);
  }
  for (; j < cnt; ++j) {
    int r = csr_src[base + j];
    float4 v = ((const float4*)xs)[r];
    a.x += v.x; a.y += v.y; a.z += v.z; a.w += v.w;
  }
  float4 o = make_float4(dc * a.x, dc * a.y, dc * a.z, dc * a.w);
  ((float4*)aggx)[c] = o;
}

// ---------------- fused MFMA gemm: h1 = relu(aggx@W1+b1) (bf16, LDS); t2s = dis*(h1@W2) bf16 ----------------
// 64 nodes x 128 cols per block, 4 waves. 16x16x32 bf16 MFMA.
// A-frag: A[m=lane&15][k=quad*8+j]; B-frag: B[k=quad*8+j][n=lane&15] (B staged transposed);
// C/D: row=quad*4+reg, col=lane&15 (m89/m91-verified).
__global__ __launch_bounds__(256) void k_gemm(const float* __restrict__ aggx, const float* __restrict__ W1,
                                              const float* __restrict__ b1, const float* __restrict__ W2,
                                              const float* __restrict__ dis, ushort_t* __restrict__ t2, int N) {
  __shared__ ushort_t h1s[64 * 264];   // [node][k], pad 256->264
  __shared__ ushort_t w2t[128 * 72];   // [n][k_local], k-chunk of 64, pad->72
  __shared__ float axs[64][4];
  __shared__ float w1s[1024];
  __shared__ float b1s[256];
  int tid = threadIdx.x;
  int node0 = blockIdx.x * 64;
  {
    int n = tid >> 2, k = tid & 3;
    int node = node0 + n;
    axs[n][k] = (node < N) ? aggx[node * 4 + k] : 0.f;
#pragma unroll
    for (int q = 0; q < 4; ++q) w1s[tid + 256 * q] = W1[tid + 256 * q];
    b1s[tid] = b1[tid];
  }
  __syncthreads();
  // h1 compute: thread t handles node t>>2, col-pairs [(t&3)*32, +32)
  {
    int n = tid >> 2;
    float a0 = axs[n][0], a1 = axs[n][1], a2 = axs[n][2], a3 = axs[n][3];
    int cp0 = (tid & 3) * 32;
    uint_t* h1w = (uint_t*)h1s;
#pragma unroll 4
    for (int q = 0; q < 32; ++q) {
      int cp = cp0 + q, c = cp * 2;
      float v0 = b1s[c], v1 = b1s[c + 1];
      v0 = fmaf(a0, w1s[c], v0);         v1 = fmaf(a0, w1s[c + 1], v1);
      v0 = fmaf(a1, w1s[256 + c], v0);   v1 = fmaf(a1, w1s[256 + c + 1], v1);
      v0 = fmaf(a2, w1s[512 + c], v0);   v1 = fmaf(a2, w1s[512 + c + 1], v1);
      v0 = fmaf(a3, w1s[768 + c], v0);   v1 = fmaf(a3, w1s[768 + c + 1], v1);
      v0 = fmaxf(v0, 0.f); v1 = fmaxf(v1, 0.f);
      h1w[n * 132 + cp] = (uint_t)bf16_1(v0) | ((uint_t)bf16_1(v1) << 16);
    }
  }
  int wv = tid >> 6, lane = tid & 63;
  int quad = lane >> 4, sel = lane & 15;
  f32x4 acc[4][2];
#pragma unroll
  for (int m = 0; m < 4; ++m)
#pragma unroll
    for (int i = 0; i < 2; ++i) acc[m][i] = (f32x4){0.f, 0.f, 0.f, 0.f};
  for (int k0 = 0; k0 < 256; k0 += 64) {
#pragma unroll 4
    for (int q = 0; q < 32; ++q) {
      int idx = tid + 256 * q;
      int n = idx & 127, kl = idx >> 7;
      w2t[n * 72 + kl] = bf16_1(W2[(size_t)(k0 + kl) * 128 + n]);
    }
    __syncthreads();
#pragma unroll
    for (int kk = 0; kk < 2; ++kk) {
      int klocal = kk * 32 + quad * 8;
      bf16x8 bf0 = *(const bf16x8*)&w2t[(wv * 32 + sel) * 72 + klocal];
      bf16x8 bf1 = *(const bf16x8*)&w2t[(wv * 32 + 16 + sel) * 72 + klocal];
#pragma unroll
      for (int m = 0; m < 4; ++m) {
        bf16x8 af = *(const bf16x8*)&h1s[(m * 16 + sel) * 264 + k0 + klocal];
        acc[m][0] = __builtin_amdgcn_mfma_f32_16x16x32_bf16(af, bf0, acc[m][0], 0, 0, 0);
        acc[m][1] = __builtin_amdgcn_mfma_f32_16x16x32_bf16(af, bf1, acc[m][1], 0, 0, 0);
      }
    }
    __syncthreads();
  }
  // epilogue: D[row=quad*4+r][col=lane&15], scale by dis[node], store bf16
#pragma unroll
  for (int m = 0; m < 4; ++m) {
#pragma unroll
    for (int r = 0; r < 4; ++r) {
      int node = node0 + m * 16 + quad * 4 + r;
      if (node < N) {
        float dn = dis[node];
#pragma unroll
        for (int i = 0; i < 2; ++i) {
          int colG = wv * 32 + i * 16 + sel;
          t2[(size_t)node * 128 + colG] = bf16_1(dn * acc[m][i][r]);
        }
      }
    }
  }
}

// ---------------- layer-2 aggregation (pre-scaled bf16 t2s) + relu + mean-pool ----------------
// One wave per node; lane l holds dims 2l,2l+1 (one dword -> 256B coalesced row read).
// Edge loop is pure adds: weights folded into t2s. 8 row-loads in flight.
__global__ __launch_bounds__(256) void k_agg2(const int* __restrict__ csr_src, const int* __restrict__ col_off,
                                              const int* __restrict__ deg, const float* __restrict__ dis,
                                              const ushort_t* __restrict__ t2s, const float* __restrict__ b2,
                                              float* __restrict__ pool, int N) {
  int wave = threadIdx.x >> 6;
  int lane = threadIdx.x & 63;
  int gw = blockIdx.x * 4 + wave;
  int nw = gridDim.x * 4;
  float2 bb = *(const float2*)&b2[lane * 2];
  float p0 = 0.f, p1 = 0.f;
  for (int c = gw; c < N; c += nw) {
    float dc = dis[c];
    int base = col_off[c];
    int cnt = deg[c] - 1;
    uint_t us = *(const uint_t*)(t2s + (size_t)c * 128 + lane * 2);
    float a0 = bf_lo(us), a1 = bf_hi(us);
    for (int j0 = 0; j0 < cnt; j0 += 64) {
      int nb = min(64, cnt - j0);
      int rl = (lane < nb) ? csr_src[base + j0 + lane] : 0;
      int j = 0;
      for (; j + 8 <= nb; j += 8) {
        int r0 = __shfl(rl, j, 64),     r1 = __shfl(rl, j + 1, 64);
        int r2 = __shfl(rl, j + 2, 64), r3 = __shfl(rl, j + 3, 64);
        int r4 = __shfl(rl, j + 4, 64), r5 = __shfl(rl, j + 5, 64);
        int r6 = __shfl(rl, j + 6, 64), r7 = __shfl(rl, j + 7, 64);
        uint_t u0 = *(const uint_t*)(t2s + (size_t)r0 * 128 + lane * 2);
        uint_t u1 = *(const uint_t*)(t2s + (size_t)r1 * 128 + lane * 2);
        uint_t u2 = *(const uint_t*)(t2s + (size_t)r2 * 128 + lane * 2);
        uint_t u3 = *(const uint_t*)(t2s + (size_t)r3 * 128 + lane * 2);
        uint_t u4 = *(const uint_t*)(t2s + (size_t)r4 * 128 + lane * 2);
        uint_t u5 = *(const uint_t*)(t2s + (size_t)r5 * 128 + lane * 2);
        uint_t u6 = *(const uint_t*)(t2s + (size_t)r6 * 128 + lane * 2);
        uint_t u7 = *(const uint_t*)(t2s + (size_t)r7 * 128 + lane * 2);
        a0 += ((bf_lo(u0) + bf_lo(u1)) + (bf_lo(u2) + bf_lo(u3))) +
              ((bf_lo(u4) + bf_lo(u5)) + (bf_lo(u6) + bf_lo(u7)));
        a1 += ((bf_hi(u0) + bf_hi(u1)) + (bf_hi(u2) + bf_hi(u3))) +
              ((bf_hi(u4) + bf_hi(u5)) + (bf_hi(u6) + bf_hi(u7)));
      }
      for (; j < nb; ++j) {
        int r = __shfl(rl, j, 64);
        uint_t u = *(const uint_t*)(t2s + (size_t)r * 128 + lane * 2);
        a0 += bf_lo(u);
        a1 += bf_hi(u);
      }
    }
    p0 += fmaxf(fmaf(dc, a0, bb.x), 0.f);
    p1 += fmaxf(fmaf(dc, a1, bb.y), 0.f);
  }
  __shared__ float red[4][128];
  red[wave][lane * 2] = p0;
  red[wave][lane * 2 + 1] = p1;
  __syncthreads();
  if (threadIdx.x < 128) {
    float s = red[0][threadIdx.x] + red[1][threadIdx.x] + red[2][threadIdx.x] + red[3][threadIdx.x];
    atomicAdd(&pool[threadIdx.x], s);
  }
}

// ---------------- final ----------------
__global__ __launch_bounds__(128) void k_final(const float* __restrict__ pool, const float* __restrict__ Wl,
                                               const float* __restrict__ bl, float* __restrict__ out, float invN) {
  __shared__ float red[128];
  int t = threadIdx.x;
  red[t] = pool[t] * invN * Wl[t];
  __syncthreads();
  for (int s = 64; s > 0; s >>= 1) {
    if (t < s) red[t] += red[t + s];
    __syncthreads();
  }
  if (t == 0) out[0] = 1.f / (1.f + expf(-(red[0] + bl[0])));
}

extern "C" void kernel_launch(void* const* d_in, const int* in_sizes, int n_in,
                              void* d_out, int out_size, void* d_ws, size_t ws_size,
                              hipStream_t stream) {
  const float* x  = (const float*)d_in[0];
  const int*   ei = (const int*)d_in[1];
  const float* W1 = (const float*)d_in[2];
  const float* b1 = (const float*)d_in[3];
  const float* W2 = (const float*)d_in[4];
  const float* b2 = (const float*)d_in[5];
  const float* Wl = (const float*)d_in[6];
  const float* bl = (const float*)d_in[7];
  int N = in_sizes[0] / 4;
  int E = in_sizes[1] / 2;
  const int* row = ei;
  const int* col = ei + E;

  char* w = (char*)d_ws;
  size_t off = 0;
  auto alloc = [&](size_t bytes) {
    void* p = w + off;
    off += (bytes + 255) & ~(size_t)255;
    return p;
  };
  int*      deg     = (int*)alloc((size_t)N * 4);
  float*    dis     = (float*)alloc((size_t)N * 4);
  int*      col_off = (int*)alloc((size_t)N * 4);
  int*      cursor  = (int*)alloc((size_t)N * 4);
  int*      csr_src = (int*)alloc((size_t)E * 4);
  float*    xs      = (float*)alloc((size_t)N * 16);
  float*    aggx    = (float*)alloc((size_t)N * 16);
  ushort_t* t2      = (ushort_t*)alloc((size_t)N * H2 * 2);
  float*    pool    = (float*)alloc(H2 * 4);
  int*      total   = (int*)alloc(4);
  (void)ws_size; (void)n_in; (void)out_size;

  int gN = (N + 255) / 256;
  int gE = (E + 255) / 256;

  k_init<<<gN, 256, 0, stream>>>(deg, cursor, pool, total, N);
  k_degree<<<gE, 256, 0, stream>>>(col, deg, E);
  k_offs<<<gN, 256, 0, stream>>>(deg, x, dis, xs, col_off, total, N);
  k_scatter<<<gE, 256, 0, stream>>>(row, col, col_off, cursor, csr_src, E);
  k_l1gather<<<gN, 256, 0, stream>>>(xs, csr_src, col_off, deg, dis, aggx, N);
  k_gemm<<<(N + 63) / 64, 256, 0, stream>>>(aggx, W1, b1, W2, dis, t2, N);
  k_agg2<<<4096, 256, 0, stream>>>(csr_src, col_off, deg, dis, t2, b2, pool, N);
  k_final<<<1, 128, 0, stream>>>(pool, Wl, bl, (float*)d_out, 1.0f / (float)N);
}

// Round 5
// 386.093 us; speedup vs baseline: 1.5332x; 1.2313x over previous
//
#include <hip/hip_runtime.h>
#include <math.h>

#define H2 128

typedef unsigned short ushort_t;
typedef unsigned int uint_t;
typedef __attribute__((ext_vector_type(8))) short bf16x8;
typedef __attribute__((ext_vector_type(4))) float f32x4;
typedef __attribute__((ext_vector_type(2))) float f32x2;

static __device__ inline ushort_t bf16_1(float f) {
  uint_t u = __float_as_uint(f);
  u += 0x7fffu + ((u >> 16) & 1u);
  return (ushort_t)(u >> 16);
}
static __device__ inline float bf_up(ushort_t s) { return __uint_as_float((uint_t)s << 16); }

// ---------------- init ----------------
__global__ __launch_bounds__(256) void k_init(int* __restrict__ deg, float* __restrict__ pool,
                                              int* __restrict__ total, int N) {
  int i = blockIdx.x * 256 + threadIdx.x;
  if (i < N) deg[i] = 1;
  if (i < H2) pool[i] = 0.f;
  if (i == 0) *total = 0;
}

// ---------------- in-degree histogram + per-edge rank (atomic return) ----------------
__global__ __launch_bounds__(256) void k_degree(const int* __restrict__ col, int* __restrict__ deg,
                                                int* __restrict__ rank, int E) {
  int e = blockIdx.x * 256 + threadIdx.x;
  if (e < E) rank[e] = atomicAdd(&deg[col[e]], 1);   // rank in [1, deg)
}

// ---------------- dis = rsqrt(deg); xs = dis*x; col_off via wave-prefix + 1 atomic/wave ----------------
__global__ __launch_bounds__(256) void k_offs(const int* __restrict__ deg, const float* __restrict__ x,
                                              float* __restrict__ dis, float* __restrict__ xs,
                                              int* __restrict__ col_off, int* __restrict__ total, int N) {
  int i = blockIdx.x * 256 + threadIdx.x;
  int lane = threadIdx.x & 63;
  int d = (i < N) ? deg[i] : 1;
  float di = rsqrtf((float)d);
  if (i < N) {
    dis[i] = di;
    float4 xv = ((const float4*)x)[i];
    ((float4*)xs)[i] = make_float4(di * xv.x, di * xv.y, di * xv.z, di * xv.w);
  }
  int v = d - 1;
  int pref = v;
#pragma unroll
  for (int s = 1; s < 64; s <<= 1) {
    int t = __shfl_up(pref, s, 64);
    if (lane >= s) pref += t;
  }
  int wavesum = __shfl(pref, 63, 64);
  int base = 0;
  if (lane == 63) base = atomicAdd(total, wavesum);
  base = __shfl(base, 63, 64);
  if (i < N) col_off[i] = base + pref - v;
}

// ---------------- scatter edges into CSR-by-destination (atomic-free via rank) ----------------
__global__ __launch_bounds__(256) void k_scatter(const int* __restrict__ row, const int* __restrict__ col,
                                                 const int* __restrict__ col_off, const int* __restrict__ rank,
                                                 int* __restrict__ csr_src, int E) {
  int e = blockIdx.x * 256 + threadIdx.x;
  if (e < E) {
    int c = col[e];
    csr_src[col_off[c] + rank[e] - 1] = row[e];
  }
}

// ---------------- layer-1 aggregation: aggx[c] = dc*(xs[c] + sum xs[r]) ----------------
__global__ __launch_bounds__(256) void k_l1gather(const float* __restrict__ xs, const int* __restrict__ csr_src,
                                                  const int* __restrict__ col_off, const int* __restrict__ deg,
                                                  const float* __restrict__ dis, float* __restrict__ aggx, int N) {
  int c = blockIdx.x * 256 + threadIdx.x;
  if (c >= N) return;
  float dc = dis[c];
  int base = col_off[c];
  int cnt = deg[c] - 1;
  float4 a = ((const float4*)xs)[c];
  int j = 0;
  for (; j + 4 <= cnt; j += 4) {
    int r0 = csr_src[base + j], r1 = csr_src[base + j + 1];
    int r2 = csr_src[base + j + 2], r3 = csr_src[base + j + 3];
    float4 v0 = ((const float4*)xs)[r0];
    float4 v1 = ((const float4*)xs)[r1];
    float4 v2 = ((const float4*)xs)[r2];
    float4 v3 = ((const float4*)xs)[r3];
    a.x += (v0.x + v1.x) + (v2.x + v3.x);
    a.y += (v0.y + v1.y) + (v2.y + v3.y);
    a.z += (v0.z + v1.z) + (v2.z + v3.z);
    a.w += (v0.w + v1.w) + (v2.w + v3.w);
  }
  for (; j < cnt; ++j) {
    int r = csr_src[base + j];
    float4 v = ((const float4*)xs)[r];
    a.x += v.x; a.y += v.y; a.z += v.z; a.w += v.w;
  }
  ((float4*)aggx)[c] = make_float4(dc * a.x, dc * a.y, dc * a.z, dc * a.w);
}

// ---------------- fused MFMA gemm: h1 = relu(aggx@W1+b1); t2f8 = fp8(dis*(h1@W2)) ----------------
// 64 nodes x 128 cols per block, 4 waves, 16x16x32 bf16 MFMA (m89/m91-verified layouts).
// Epilogue: bf16 LDS bounce (reuse w2t) -> HW cvt_pk_fp8_f32 pack -> coalesced dword stores.
__global__ __launch_bounds__(256) void k_gemm(const float* __restrict__ aggx, const float* __restrict__ W1,
                                              const float* __restrict__ b1, const float* __restrict__ W2,
                                              const float* __restrict__ dis, uint_t* __restrict__ t2f8, int N) {
  __shared__ ushort_t h1s[64 * 264];   // [node][k], pad 256->264
  __shared__ ushort_t w2t[128 * 72];   // [n][k_local] k-chunk 64, pad->72; reused as epilogue tile
  __shared__ float axs[64][4];
  __shared__ float w1s[1024];
  __shared__ float b1s[256];
  int tid = threadIdx.x;
  int node0 = blockIdx.x * 64;
  {
    int n = tid >> 2, k = tid & 3;
    int node = node0 + n;
    axs[n][k] = (node < N) ? aggx[node * 4 + k] : 0.f;
#pragma unroll
    for (int q = 0; q < 4; ++q) w1s[tid + 256 * q] = W1[tid + 256 * q];
    b1s[tid] = b1[tid];
  }
  __syncthreads();
  {
    int n = tid >> 2;
    float a0 = axs[n][0], a1 = axs[n][1], a2 = axs[n][2], a3 = axs[n][3];
    int cp0 = (tid & 3) * 32;
    uint_t* h1w = (uint_t*)h1s;
#pragma unroll 4
    for (int q = 0; q < 32; ++q) {
      int cp = cp0 + q, c = cp * 2;
      float v0 = b1s[c], v1 = b1s[c + 1];
      v0 = fmaf(a0, w1s[c], v0);         v1 = fmaf(a0, w1s[c + 1], v1);
      v0 = fmaf(a1, w1s[256 + c], v0);   v1 = fmaf(a1, w1s[256 + c + 1], v1);
      v0 = fmaf(a2, w1s[512 + c], v0);   v1 = fmaf(a2, w1s[512 + c + 1], v1);
      v0 = fmaf(a3, w1s[768 + c], v0);   v1 = fmaf(a3, w1s[768 + c + 1], v1);
      v0 = fmaxf(v0, 0.f); v1 = fmaxf(v1, 0.f);
      h1w[n * 132 + cp] = (uint_t)bf16_1(v0) | ((uint_t)bf16_1(v1) << 16);
    }
  }
  int wv = tid >> 6, lane = tid & 63;
  int quad = lane >> 4, sel = lane & 15;
  f32x4 acc[4][2];
#pragma unroll
  for (int m = 0; m < 4; ++m)
#pragma unroll
    for (int i = 0; i < 2; ++i) acc[m][i] = (f32x4){0.f, 0.f, 0.f, 0.f};
  for (int k0 = 0; k0 < 256; k0 += 64) {
#pragma unroll 4
    for (int q = 0; q < 32; ++q) {
      int idx = tid + 256 * q;
      int n = idx & 127, kl = idx >> 7;
      w2t[n * 72 + kl] = bf16_1(W2[(size_t)(k0 + kl) * 128 + n]);
    }
    __syncthreads();
#pragma unroll
    for (int kk = 0; kk < 2; ++kk) {
      int klocal = kk * 32 + quad * 8;
      bf16x8 bf0 = *(const bf16x8*)&w2t[(wv * 32 + sel) * 72 + klocal];
      bf16x8 bf1 = *(const bf16x8*)&w2t[(wv * 32 + 16 + sel) * 72 + klocal];
#pragma unroll
      for (int m = 0; m < 4; ++m) {
        bf16x8 af = *(const bf16x8*)&h1s[(m * 16 + sel) * 264 + k0 + klocal];
        acc[m][0] = __builtin_amdgcn_mfma_f32_16x16x32_bf16(af, bf0, acc[m][0], 0, 0, 0);
        acc[m][1] = __builtin_amdgcn_mfma_f32_16x16x32_bf16(af, bf1, acc[m][1], 0, 0, 0);
      }
    }
    __syncthreads();
  }
  // epilogue: scale by dis[node], bounce through LDS (bf16), pack fp8 dwords, coalesced store
  ushort_t* tile = w2t;   // [64][132]
#pragma unroll
  for (int m = 0; m < 4; ++m) {
#pragma unroll
    for (int r = 0; r < 4; ++r) {
      int rl = m * 16 + quad * 4 + r;
      int node = node0 + rl;
      float dn = (node < N) ? dis[node] : 0.f;
      tile[rl * 132 + wv * 32 + sel]      = bf16_1(dn * acc[m][0][r]);
      tile[rl * 132 + wv * 32 + 16 + sel] = bf16_1(dn * acc[m][1][r]);
    }
  }
  __syncthreads();
#pragma unroll
  for (int q = 0; q < 8; ++q) {
    int idx = tid + 256 * q;
    int rl = idx >> 5, dwc = idx & 31;
    int node = node0 + rl;
    if (node < N) {
      const ushort_t* src = &tile[rl * 132 + dwc * 4];
      float f0 = bf_up(src[0]), f1 = bf_up(src[1]), f2 = bf_up(src[2]), f3 = bf_up(src[3]);
      int wrd = __builtin_amdgcn_cvt_pk_fp8_f32(f0, f1, 0, false);
      wrd = __builtin_amdgcn_cvt_pk_fp8_f32(f2, f3, wrd, true);
      t2f8[(size_t)node * 32 + dwc] = (uint_t)wrd;
    }
  }
}

// ---------------- layer-2 aggregation (fp8 t2, pre-scaled) + relu + mean-pool ----------------
// Wave = 2 halves x 32 lanes; halves process alternating edges; lane hl covers dims
// 4hl..4hl+3 (one dword = 4 fp8). 8 loads in flight = 16 edges per chunk.
__global__ __launch_bounds__(256) void k_agg2(const int* __restrict__ csr_src, const int* __restrict__ col_off,
                                              const int* __restrict__ deg, const float* __restrict__ dis,
                                              const unsigned char* __restrict__ t2f8, const float* __restrict__ b2,
                                              float* __restrict__ pool, int N) {
  int wave = threadIdx.x >> 6;
  int lane = threadIdx.x & 63;
  int half = lane >> 5;
  int hl = lane & 31;
  int gw = blockIdx.x * 4 + wave;
  int nw = gridDim.x * 4;
  float4 bb = *(const float4*)&b2[hl * 4];
  float4 pacc = make_float4(0.f, 0.f, 0.f, 0.f);
  for (int c = gw; c < N; c += nw) {
    float dc = dis[c];
    int base = col_off[c];
    int cnt = deg[c] - 1;
    f32x2 a01 = {0.f, 0.f}, a23 = {0.f, 0.f};
    for (int j0 = 0; j0 < cnt; j0 += 64) {
      int nb = min(64, cnt - j0);
      int rl = (lane < nb) ? csr_src[base + j0 + lane] : 0;
      int j = 0;
      for (; j + 16 <= nb; j += 16) {
        uint_t u[8];
#pragma unroll
        for (int q = 0; q < 8; ++q) {
          int r = __shfl(rl, j + 2 * q + half, 64);
          u[q] = *(const uint_t*)(t2f8 + ((size_t)r << 7) + (hl << 2));
        }
#pragma unroll
        for (int q = 0; q < 8; ++q) {
          a01 += __builtin_amdgcn_cvt_pk_f32_fp8(u[q], false);
          a23 += __builtin_amdgcn_cvt_pk_f32_fp8(u[q], true);
        }
      }
      if (j < nb) {
#pragma unroll
        for (int q = 0; q < 8; ++q) {
          int e = j + 2 * q + half;
          int r = __shfl(rl, min(e, nb - 1), 64);
          uint_t u = *(const uint_t*)(t2f8 + ((size_t)r << 7) + (hl << 2));
          if (e >= nb) u = 0;
          a01 += __builtin_amdgcn_cvt_pk_f32_fp8(u, false);
          a23 += __builtin_amdgcn_cvt_pk_f32_fp8(u, true);
        }
      }
    }
    if (half == 0) {   // self term once
      uint_t u = *(const uint_t*)(t2f8 + ((size_t)c << 7) + (hl << 2));
      a01 += __builtin_amdgcn_cvt_pk_f32_fp8(u, false);
      a23 += __builtin_amdgcn_cvt_pk_f32_fp8(u, true);
    }
    float s0 = a01.x + __shfl_xor(a01.x, 32, 64);
    float s1 = a01.y + __shfl_xor(a01.y, 32, 64);
    float s2 = a23.x + __shfl_xor(a23.x, 32, 64);
    float s3 = a23.y + __shfl_xor(a23.y, 32, 64);
    pacc.x += fmaxf(fmaf(dc, s0, bb.x), 0.f);
    pacc.y += fmaxf(fmaf(dc, s1, bb.y), 0.f);
    pacc.z += fmaxf(fmaf(dc, s2, bb.z), 0.f);
    pacc.w += fmaxf(fmaf(dc, s3, bb.w), 0.f);
  }
  __shared__ float red[4][128];
  if (half == 0) *(float4*)&red[wave][hl * 4] = pacc;
  __syncthreads();
  if (threadIdx.x < 128) {
    float s = red[0][threadIdx.x] + red[1][threadIdx.x] + red[2][threadIdx.x] + red[3][threadIdx.x];
    atomicAdd(&pool[threadIdx.x], s);
  }
}

// ---------------- final ----------------
__global__ __launch_bounds__(128) void k_final(const float* __restrict__ pool, const float* __restrict__ Wl,
                                               const float* __restrict__ bl, float* __restrict__ out, float invN) {
  __shared__ float red[128];
  int t = threadIdx.x;
  red[t] = pool[t] * invN * Wl[t];
  __syncthreads();
  for (int s = 64; s > 0; s >>= 1) {
    if (t < s) red[t] += red[t + s];
    __syncthreads();
  }
  if (t == 0) out[0] = 1.f / (1.f + expf(-(red[0] + bl[0])));
}

extern "C" void kernel_launch(void* const* d_in, const int* in_sizes, int n_in,
                              void* d_out, int out_size, void* d_ws, size_t ws_size,
                              hipStream_t stream) {
  const float* x  = (const float*)d_in[0];
  const int*   ei = (const int*)d_in[1];
  const float* W1 = (const float*)d_in[2];
  const float* b1 = (const float*)d_in[3];
  const float* W2 = (const float*)d_in[4];
  const float* b2 = (const float*)d_in[5];
  const float* Wl = (const float*)d_in[6];
  const float* bl = (const float*)d_in[7];
  int N = in_sizes[0] / 4;
  int E = in_sizes[1] / 2;
  const int* row = ei;
  const int* col = ei + E;

  char* w = (char*)d_ws;
  size_t off = 0;
  auto alloc = [&](size_t bytes) {
    void* p = w + off;
    off += (bytes + 255) & ~(size_t)255;
    return p;
  };
  int*      deg     = (int*)alloc((size_t)N * 4);
  float*    dis     = (float*)alloc((size_t)N * 4);
  int*      col_off = (int*)alloc((size_t)N * 4);
  int*      rank    = (int*)alloc((size_t)E * 4);
  int*      csr_src = (int*)alloc((size_t)E * 4);
  float*    xs      = (float*)alloc((size_t)N * 16);
  float*    aggx    = (float*)alloc((size_t)N * 16);
  uint_t*   t2f8    = (uint_t*)alloc((size_t)N * H2);
  float*    pool    = (float*)alloc(H2 * 4);
  int*      total   = (int*)alloc(4);
  (void)ws_size; (void)n_in; (void)out_size;

  int gN = (N + 255) / 256;
  int gE = (E + 255) / 256;

  k_init<<<gN, 256, 0, stream>>>(deg, pool, total, N);
  k_degree<<<gE, 256, 0, stream>>>(col, deg, rank, E);
  k_offs<<<gN, 256, 0, stream>>>(deg, x, dis, xs, col_off, total, N);
  k_scatter<<<gE, 256, 0, stream>>>(row, col, col_off, rank, csr_src, E);
  k_l1gather<<<gN, 256, 0, stream>>>(xs, csr_src, col_off, deg, dis, aggx, N);
  k_gemm<<<(N + 63) / 64, 256, 0, stream>>>(aggx, W1, b1, W2, dis, t2f8, N);
  k_agg2<<<4096, 256, 0, stream>>>(csr_src, col_off, deg, dis, (const unsigned char*)t2f8, b2, pool, N);
  k_final<<<1, 128, 0, stream>>>(pool, Wl, bl, (float*)d_out, 1.0f / (float)N);
}

// Round 6
// 366.568 us; speedup vs baseline: 1.6148x; 1.0533x over previous
//
#include <hip/hip_runtime.h>
#include <math.h>

#define H2 128

typedef unsigned short ushort_t;
typedef unsigned int uint_t;
typedef __attribute__((ext_vector_type(8))) short bf16x8;
typedef __attribute__((ext_vector_type(4))) float f32x4;
typedef __attribute__((ext_vector_type(2))) float f32x2;

static __device__ inline ushort_t bf16_1(float f) {
  uint_t u = __float_as_uint(f);
  u += 0x7fffu + ((u >> 16) & 1u);
  return (ushort_t)(u >> 16);
}
static __device__ inline float bf_up(ushort_t s) { return __uint_as_float((uint_t)s << 16); }

// ---------------- in-degree histogram + per-edge rank (deg pre-zeroed by memset) ----------------
__global__ __launch_bounds__(256) void k_degree(const int* __restrict__ col, int* __restrict__ deg,
                                                int* __restrict__ rank, int E) {
  int e = blockIdx.x * 256 + threadIdx.x;
  if (e < E) rank[e] = atomicAdd(&deg[col[e]], 1);   // rank in [0, indeg)
}

// ---------------- dis = rsqrt(indeg+1); xs = dis*x; col_off via wave-prefix + 1 atomic/wave ----------------
__global__ __launch_bounds__(256) void k_offs(const int* __restrict__ deg, const float* __restrict__ x,
                                              float* __restrict__ dis, float* __restrict__ xs,
                                              int* __restrict__ col_off, int* __restrict__ total, int N) {
  int i = blockIdx.x * 256 + threadIdx.x;
  int lane = threadIdx.x & 63;
  int v = (i < N) ? deg[i] : 0;          // in-edge count (self-loop excluded)
  float di = rsqrtf((float)(v + 1));
  if (i < N) {
    dis[i] = di;
    float4 xv = ((const float4*)x)[i];
    ((float4*)xs)[i] = make_float4(di * xv.x, di * xv.y, di * xv.z, di * xv.w);
  }
  int pref = v;
#pragma unroll
  for (int s = 1; s < 64; s <<= 1) {
    int t = __shfl_up(pref, s, 64);
    if (lane >= s) pref += t;
  }
  int wavesum = __shfl(pref, 63, 64);
  int base = 0;
  if (lane == 63) base = atomicAdd(total, wavesum);
  base = __shfl(base, 63, 64);
  if (i < N) col_off[i] = base + pref - v;
}

// ---------------- scatter edges into CSR-by-destination (atomic-free via rank) ----------------
__global__ __launch_bounds__(256) void k_scatter(const int* __restrict__ row, const int* __restrict__ col,
                                                 const int* __restrict__ col_off, const int* __restrict__ rank,
                                                 int* __restrict__ csr_src, int E) {
  int e = blockIdx.x * 256 + threadIdx.x;
  if (e < E) {
    int c = col[e];
    csr_src[col_off[c] + rank[e]] = row[e];
  }
}

// ---------------- layer-1 aggregation: aggx[c] = dc*(xs[c] + sum xs[r]) ----------------
__global__ __launch_bounds__(256) void k_l1gather(const float* __restrict__ xs, const int* __restrict__ csr_src,
                                                  const int* __restrict__ col_off, const int* __restrict__ deg,
                                                  const float* __restrict__ dis, float* __restrict__ aggx, int N) {
  int c = blockIdx.x * 256 + threadIdx.x;
  if (c >= N) return;
  float dc = dis[c];
  int base = col_off[c];
  int cnt = deg[c];
  float4 a = ((const float4*)xs)[c];
  int j = 0;
  for (; j + 4 <= cnt; j += 4) {
    int r0 = csr_src[base + j], r1 = csr_src[base + j + 1];
    int r2 = csr_src[base + j + 2], r3 = csr_src[base + j + 3];
    float4 v0 = ((const float4*)xs)[r0];
    float4 v1 = ((const float4*)xs)[r1];
    float4 v2 = ((const float4*)xs)[r2];
    float4 v3 = ((const float4*)xs)[r3];
    a.x += (v0.x + v1.x) + (v2.x + v3.x);
    a.y += (v0.y + v1.y) + (v2.y + v3.y);
    a.z += (v0.z + v1.z) + (v2.z + v3.z);
    a.w += (v0.w + v1.w) + (v2.w + v3.w);
  }
  for (; j < cnt; ++j) {
    int r = csr_src[base + j];
    float4 v = ((const float4*)xs)[r];
    a.x += v.x; a.y += v.y; a.z += v.z; a.w += v.w;
  }
  ((float4*)aggx)[c] = make_float4(dc * a.x, dc * a.y, dc * a.z, dc * a.w);
}

// ---------------- fused MFMA gemm: h1 = relu(aggx@W1+b1); t2f8 = fp8(dis*(h1@W2)) ----------------
__global__ __launch_bounds__(256) void k_gemm(const float* __restrict__ aggx, const float* __restrict__ W1,
                                              const float* __restrict__ b1, const float* __restrict__ W2,
                                              const float* __restrict__ dis, uint_t* __restrict__ t2f8, int N) {
  __shared__ ushort_t h1s[64 * 264];   // [node][k], pad 256->264
  __shared__ ushort_t w2t[128 * 72];   // [n][k_local] k-chunk 64, pad->72; reused as epilogue tile
  __shared__ float axs[64][4];
  __shared__ float w1s[1024];
  __shared__ float b1s[256];
  int tid = threadIdx.x;
  int node0 = blockIdx.x * 64;
  {
    int n = tid >> 2, k = tid & 3;
    int node = node0 + n;
    axs[n][k] = (node < N) ? aggx[node * 4 + k] : 0.f;
#pragma unroll
    for (int q = 0; q < 4; ++q) w1s[tid + 256 * q] = W1[tid + 256 * q];
    b1s[tid] = b1[tid];
  }
  __syncthreads();
  {
    int n = tid >> 2;
    float a0 = axs[n][0], a1 = axs[n][1], a2 = axs[n][2], a3 = axs[n][3];
    int cp0 = (tid & 3) * 32;
    uint_t* h1w = (uint_t*)h1s;
#pragma unroll 4
    for (int q = 0; q < 32; ++q) {
      int cp = cp0 + q, c = cp * 2;
      float v0 = b1s[c], v1 = b1s[c + 1];
      v0 = fmaf(a0, w1s[c], v0);         v1 = fmaf(a0, w1s[c + 1], v1);
      v0 = fmaf(a1, w1s[256 + c], v0);   v1 = fmaf(a1, w1s[256 + c + 1], v1);
      v0 = fmaf(a2, w1s[512 + c], v0);   v1 = fmaf(a2, w1s[512 + c + 1], v1);
      v0 = fmaf(a3, w1s[768 + c], v0);   v1 = fmaf(a3, w1s[768 + c + 1], v1);
      v0 = fmaxf(v0, 0.f); v1 = fmaxf(v1, 0.f);
      h1w[n * 132 + cp] = (uint_t)bf16_1(v0) | ((uint_t)bf16_1(v1) << 16);
    }
  }
  int wv = tid >> 6, lane = tid & 63;
  int quad = lane >> 4, sel = lane & 15;
  f32x4 acc[4][2];
#pragma unroll
  for (int m = 0; m < 4; ++m)
#pragma unroll
    for (int i = 0; i < 2; ++i) acc[m][i] = (f32x4){0.f, 0.f, 0.f, 0.f};
  for (int k0 = 0; k0 < 256; k0 += 64) {
#pragma unroll 4
    for (int q = 0; q < 32; ++q) {
      int idx = tid + 256 * q;
      int n = idx & 127, kl = idx >> 7;
      w2t[n * 72 + kl] = bf16_1(W2[(size_t)(k0 + kl) * 128 + n]);
    }
    __syncthreads();
#pragma unroll
    for (int kk = 0; kk < 2; ++kk) {
      int klocal = kk * 32 + quad * 8;
      bf16x8 bf0 = *(const bf16x8*)&w2t[(wv * 32 + sel) * 72 + klocal];
      bf16x8 bf1 = *(const bf16x8*)&w2t[(wv * 32 + 16 + sel) * 72 + klocal];
#pragma unroll
      for (int m = 0; m < 4; ++m) {
        bf16x8 af = *(const bf16x8*)&h1s[(m * 16 + sel) * 264 + k0 + klocal];
        acc[m][0] = __builtin_amdgcn_mfma_f32_16x16x32_bf16(af, bf0, acc[m][0], 0, 0, 0);
        acc[m][1] = __builtin_amdgcn_mfma_f32_16x16x32_bf16(af, bf1, acc[m][1], 0, 0, 0);
      }
    }
    __syncthreads();
  }
  ushort_t* tile = w2t;   // [64][132]
#pragma unroll
  for (int m = 0; m < 4; ++m) {
#pragma unroll
    for (int r = 0; r < 4; ++r) {
      int rl = m * 16 + quad * 4 + r;
      int node = node0 + rl;
      float dn = (node < N) ? dis[node] : 0.f;
      tile[rl * 132 + wv * 32 + sel]      = bf16_1(dn * acc[m][0][r]);
      tile[rl * 132 + wv * 32 + 16 + sel] = bf16_1(dn * acc[m][1][r]);
    }
  }
  __syncthreads();
#pragma unroll
  for (int q = 0; q < 8; ++q) {
    int idx = tid + 256 * q;
    int rl = idx >> 5, dwc = idx & 31;
    int node = node0 + rl;
    if (node < N) {
      const ushort_t* src = &tile[rl * 132 + dwc * 4];
      float f0 = bf_up(src[0]), f1 = bf_up(src[1]), f2 = bf_up(src[2]), f3 = bf_up(src[3]);
      int wrd = __builtin_amdgcn_cvt_pk_fp8_f32(f0, f1, 0, false);
      wrd = __builtin_amdgcn_cvt_pk_fp8_f32(f2, f3, wrd, true);
      t2f8[(size_t)node * 32 + dwc] = (uint_t)wrd;
    }
  }
}

// ---------------- layer-2 aggregation (fp8, pre-scaled) + relu + mean-pool ----------------
// One wave per node; lane l covers dims 2l,2l+1 (one ushort = one 128B line per edge,
// one instruction). Edge indices go through SGPRs (readfirstlane -> s_load + uniform
// saddr loads): no DS ops in the chain, 16 loads in flight.
__global__ __launch_bounds__(256) void k_agg2(const int* __restrict__ csr_src, const int* __restrict__ col_off,
                                              const int* __restrict__ deg, const float* __restrict__ dis,
                                              const unsigned char* __restrict__ t2f8, const float* __restrict__ b2,
                                              float* __restrict__ pool, int N) {
  int wave = threadIdx.x >> 6;
  int lane = threadIdx.x & 63;
  int gw = blockIdx.x * 4 + wave;
  int nw = gridDim.x * 4;
  float2 bb = *(const float2*)&b2[lane * 2];
  float p0 = 0.f, p1 = 0.f;
  for (int c0 = gw; c0 < N; c0 += nw) {
    int c = __builtin_amdgcn_readfirstlane(c0);
    int base = __builtin_amdgcn_readfirstlane(col_off[c]);
    int cnt  = __builtin_amdgcn_readfirstlane(deg[c]);
    float dc = dis[c];
    const int* seg = csr_src + base;
    uint_t us = *(const ushort_t*)(t2f8 + ((size_t)c << 7) + (lane << 1));
    f32x2 a = __builtin_amdgcn_cvt_pk_f32_fp8(us, false);   // self term
    int j = 0;
    for (; j + 16 <= cnt; j += 16) {
      uint_t u[16];
#pragma unroll
      for (int q = 0; q < 16; ++q) {
        int r = __builtin_amdgcn_readfirstlane(seg[j + q]);
        u[q] = *(const ushort_t*)(t2f8 + ((size_t)r << 7) + (lane << 1));
      }
#pragma unroll
      for (int q = 0; q < 16; ++q) a += __builtin_amdgcn_cvt_pk_f32_fp8(u[q], false);
    }
    for (; j < cnt; ++j) {
      int r = __builtin_amdgcn_readfirstlane(seg[j]);
      uint_t u = *(const ushort_t*)(t2f8 + ((size_t)r << 7) + (lane << 1));
      a += __builtin_amdgcn_cvt_pk_f32_fp8(u, false);
    }
    p0 += fmaxf(fmaf(dc, a.x, bb.x), 0.f);
    p1 += fmaxf(fmaf(dc, a.y, bb.y), 0.f);
  }
  __shared__ float red[4][128];
  red[wave][lane * 2] = p0;
  red[wave][lane * 2 + 1] = p1;
  __syncthreads();
  if (threadIdx.x < 128) {
    float s = red[0][threadIdx.x] + red[1][threadIdx.x] + red[2][threadIdx.x] + red[3][threadIdx.x];
    atomicAdd(&pool[threadIdx.x], s);
  }
}

// ---------------- final ----------------
__global__ __launch_bounds__(128) void k_final(const float* __restrict__ pool, const float* __restrict__ Wl,
                                               const float* __restrict__ bl, float* __restrict__ out, float invN) {
  __shared__ float red[128];
  int t = threadIdx.x;
  red[t] = pool[t] * invN * Wl[t];
  __syncthreads();
  for (int s = 64; s > 0; s >>= 1) {
    if (t < s) red[t] += red[t + s];
    __syncthreads();
  }
  if (t == 0) out[0] = 1.f / (1.f + expf(-(red[0] + bl[0])));
}

extern "C" void kernel_launch(void* const* d_in, const int* in_sizes, int n_in,
                              void* d_out, int out_size, void* d_ws, size_t ws_size,
                              hipStream_t stream) {
  const float* x  = (const float*)d_in[0];
  const int*   ei = (const int*)d_in[1];
  const float* W1 = (const float*)d_in[2];
  const float* b1 = (const float*)d_in[3];
  const float* W2 = (const float*)d_in[4];
  const float* b2 = (const float*)d_in[5];
  const float* Wl = (const float*)d_in[6];
  const float* bl = (const float*)d_in[7];
  int N = in_sizes[0] / 4;
  int E = in_sizes[1] / 2;
  const int* row = ei;
  const int* col = ei + E;

  char* w = (char*)d_ws;
  size_t off = 0;
  auto alloc = [&](size_t bytes) {
    void* p = w + off;
    off += (bytes + 255) & ~(size_t)255;
    return p;
  };
  int*      deg     = (int*)alloc((size_t)N * 4);
  float*    dis     = (float*)alloc((size_t)N * 4);
  int*      col_off = (int*)alloc((size_t)N * 4);
  int*      rank    = (int*)alloc((size_t)E * 4);
  int*      csr_src = (int*)alloc((size_t)E * 4);
  float*    xs      = (float*)alloc((size_t)N * 16);
  float*    aggx    = (float*)alloc((size_t)N * 16);
  uint_t*   t2f8    = (uint_t*)alloc((size_t)N * H2);
  float*    pool    = (float*)alloc(H2 * 4);
  int*      total   = (int*)alloc(4);
  (void)ws_size; (void)n_in; (void)out_size;

  int gN = (N + 255) / 256;
  int gE = (E + 255) / 256;

  hipMemsetAsync(deg, 0, (size_t)N * 4, stream);
  hipMemsetAsync(pool, 0, H2 * 4, stream);
  hipMemsetAsync(total, 0, 4, stream);
  k_degree<<<gE, 256, 0, stream>>>(col, deg, rank, E);
  k_offs<<<gN, 256, 0, stream>>>(deg, x, dis, xs, col_off, total, N);
  k_scatter<<<gE, 256, 0, stream>>>(row, col, col_off, rank, csr_src, E);
  k_l1gather<<<gN, 256, 0, stream>>>(xs, csr_src, col_off, deg, dis, aggx, N);
  k_gemm<<<(N + 63) / 64, 256, 0, stream>>>(aggx, W1, b1, W2, dis, t2f8, N);
  k_agg2<<<2048, 256, 0, stream>>>(csr_src, col_off, deg, dis, (const unsigned char*)t2f8, b2, pool, N);
  k_final<<<1, 128, 0, stream>>>(pool, Wl, bl, (float*)d_out, 1.0f / (float)N);
}